// Round 2
// 678.776 us; speedup vs baseline: 1.0095x; 1.0095x over previous
//
#include <hip/hip_runtime.h>
#include <cstdint>

#define E_TOTAL 320000
#define NN 10000
#define DIN 256
#define HDIM 512
#define DOUT 256
#define M_TILE 48
#define N_MAIN_BLOCKS ((E_TOTAL + M_TILE - 1) / M_TILE)  // 6667

typedef __attribute__((ext_vector_type(8))) short short8;
typedef __attribute__((ext_vector_type(8))) unsigned short ushort8;
typedef __attribute__((ext_vector_type(4))) float f32x4;

__device__ __forceinline__ unsigned short f2bf(float f) {
    union { float f; unsigned u; } v; v.f = f;
    unsigned u = v.u;
    return (unsigned short)((u + 0x7fffu + ((u >> 16) & 1u)) >> 16);  // RNE
}
__device__ __forceinline__ float bf2f(unsigned short u) {
    union { unsigned u; float f; } v; v.u = ((unsigned)u) << 16; return v.f;
}

// ---- detect whether edge_index arrived as int64 (high dwords all zero) ----
__global__ void detect_i64(const int* __restrict__ eidx, int* __restrict__ flag) {
    __shared__ int anynz;
    if (threadIdx.x == 0) anynz = 0;
    __syncthreads();
    int v = 0;
    for (int i = threadIdx.x; i < 8192; i += blockDim.x) v |= eidx[2 * i + 1];
    if (v != 0) atomicOr(&anynz, 1);
    __syncthreads();
    if (threadIdx.x == 0) *flag = (anynz == 0) ? 1 : 0;
}

// ---- x fp32 -> bf16 ----
__global__ void convert_x(const float* __restrict__ x, unsigned short* __restrict__ xb) {
    int total = NN * DIN;
    for (int i = blockIdx.x * blockDim.x + threadIdx.x; i < total; i += gridDim.x * blockDim.x)
        xb[i] = f2bf(x[i]);
}

// ---- pack W (row-major [K][ncols] fp32) into B-fragment layout for
// mfma_f32_16x16x32_bf16: lane l holds B[k=ks*32+(l>>4)*8+j][n=ct*16+(l&15)]. ----
__global__ void pack_w(const float* __restrict__ W, unsigned short* __restrict__ Wp,
                       int ncols, int nct, int nks) {
    int tid = blockIdx.x * blockDim.x + threadIdx.x;
    int total = nct * nks * 64;
    if (tid >= total) return;
    int lane = tid & 63;
    int ks = (tid >> 6) % nks;
    int ct = tid / (64 * nks);
    int k0 = ks * 32 + (lane >> 4) * 8;
    int n = ct * 16 + (lane & 15);
    short8 v;
#pragma unroll
    for (int j = 0; j < 8; j++) v[j] = (short)f2bf(W[(long)(k0 + j) * ncols + n]);
    *(short8*)(Wp + ((long)(ct * nks + ks) * 64 + lane) * 8) = v;
}

// ---- pack Wcat[256][1024]: Wcat[k][j] = (j<512) ? W1[k][j] : W1[256+k][j-512] ----
// nct=64, nks=8.
__global__ void pack_wcat(const float* __restrict__ W1, unsigned short* __restrict__ Wp) {
    int tid = blockIdx.x * blockDim.x + threadIdx.x;
    if (tid >= 64 * 8 * 64) return;
    int lane = tid & 63;
    int ks = (tid >> 6) & 7;
    int ct = tid >> 9;                 // 0..63
    int k0 = ks * 32 + (lane >> 4) * 8;
    int n = ct * 16 + (lane & 15);     // 0..1023
    int col = n & 511;
    int radd = (n >> 9) * 256;
    short8 v;
#pragma unroll
    for (int j = 0; j < 8; j++) v[j] = (short)f2bf(W1[(long)(k0 + j + radd) * HDIM + col]);
    *(short8*)(Wp + ((long)(ct * 8 + ks) * 64 + lane) * 8) = v;
}

// ---- stage 1: P[10000][1024] = xb @ Wcat (fp32 or bf16 store) ----
template<bool PF32>
__global__ __launch_bounds__(256, 2)
void node_gemm(const unsigned short* __restrict__ xb,
               const unsigned short* __restrict__ Wcp,
               void* __restrict__ Pv)
{
    __shared__ unsigned short xs[64 * 256];  // 32 KiB, XOR-swizzled 16B chunks
    const int tid = threadIdx.x;
    const int lane = tid & 63;
    const int w = tid >> 6;
    const int lo = lane & 15;
    const int quad = lane >> 4;
    const int rt0 = blockIdx.x;
    const int cq = blockIdx.y;

#pragma unroll
    for (int i = 0; i < 8; i++) {
        int rp = i * 4 + w;                   // wave-uniform row pair 0..31
        int r = rp * 2 + (lane >> 5);         // local row of this lane's chunk
        int node = rt0 * 64 + r;
        if (node > NN - 1) node = NN - 1;
        int cs = (lane & 31) ^ (r & 7);       // pre-swizzled source chunk
        const unsigned short* g = xb + (long)node * DIN + cs * 8;
        unsigned roff = __builtin_amdgcn_readfirstlane((unsigned)(rp * 512));
        __builtin_amdgcn_global_load_lds(
            (const __attribute__((address_space(1))) void*)g,
            (__attribute__((address_space(3))) void*)(xs + roff),
            16, 0, 0);
    }
    __syncthreads();

    f32x4 acc[4][4];
#pragma unroll
    for (int rt = 0; rt < 4; rt++)
#pragma unroll
        for (int ct = 0; ct < 4; ct++) acc[rt][ct] = (f32x4){0.f, 0.f, 0.f, 0.f};

    short8 ap[2][4], bp[2][4];
    auto loadA = [&](short8* d, int ks) {
#pragma unroll
        for (int rt = 0; rt < 4; rt++) {
            int m = rt * 16 + lo;
            int c = (ks * 4 + quad) ^ (m & 7);
            d[rt] = *(const short8*)(xs + m * 256 + c * 8);
        }
    };
    auto loadB = [&](short8* d, int ks) {
#pragma unroll
        for (int ct = 0; ct < 4; ct++) {
            int ctg = cq * 16 + w * 4 + ct;
            d[ct] = *(const short8*)(Wcp + ((long)(ctg * 8 + ks) * 64 + lane) * 8);
        }
    };
    loadA(ap[0], 0);
    loadB(bp[0], 0);
#pragma unroll
    for (int ks = 0; ks < 8; ks++) {
        int cur = ks & 1, nxt = cur ^ 1;
        if (ks < 7) { loadA(ap[nxt], ks + 1); loadB(bp[nxt], ks + 1); }
#pragma unroll
        for (int ct = 0; ct < 4; ct++)
#pragma unroll
            for (int rt = 0; rt < 4; rt++)
                acc[rt][ct] = __builtin_amdgcn_mfma_f32_16x16x32_bf16(
                    ap[cur][rt], bp[cur][ct], acc[rt][ct], 0, 0, 0);
    }

#pragma unroll
    for (int rt = 0; rt < 4; rt++) {
#pragma unroll
        for (int rr = 0; rr < 4; rr++) {
            int r = rt0 * 64 + rt * 16 + quad * 4 + rr;
            if (r < NN) {
                long off = (long)r * 1024 + cq * 256 + w * 64 + lo;
#pragma unroll
                for (int ct = 0; ct < 4; ct++) {
                    float v = acc[rt][ct][rr];
                    if constexpr (PF32) ((float*)Pv)[off + ct * 16] = v;
                    else ((unsigned short*)Pv)[off + ct * 16] = f2bf(v);
                }
            }
        }
    }
}

// ---- stage 2: per 64-edge tile: h = relu(P[s][:512]+P[t][512:]+b1) -> GEMM2 -> out ----
template<bool PF32>
__global__ __launch_bounds__(256, 2)
void edge_out(const void* __restrict__ Pv,
              const int* __restrict__ eidx,
              const float* __restrict__ b1,
              const unsigned short* __restrict__ W2p,
              const float* __restrict__ b2,
              const int* __restrict__ flag,
              float* __restrict__ out)
{
    __shared__ unsigned short hs[64 * 512];  // 64 KiB, XOR-swizzled
    const int tid = threadIdx.x;
    const int lane = tid & 63;
    const int w = tid >> 6;
    const int lo = lane & 15;
    const int quad = lane >> 4;
    const long e0 = (long)blockIdx.x * 64;

    // ---- gather + add + bias + relu -> hs ----
    {
        const bool is64 = (*flag != 0);
        const int rw = tid & 63;    // edge row this thread fills
        const int q = tid >> 6;     // feature quarter (128 of 512)
        long e = e0 + rw;
        long sn, tn;
        if (is64) {
            sn = ((const long long*)eidx)[e];
            tn = ((const long long*)eidx)[E_TOTAL + e];
        } else {
            sn = eidx[e];
            tn = eidx[E_TOTAL + e];
        }
        if (sn < 0) sn = 0; if (sn > NN - 1) sn = NN - 1;
        if (tn < 0) tn = 0; if (tn > NN - 1) tn = NN - 1;
        const float* bb = b1 + q * 128;
        if constexpr (PF32) {
            const float* Ar = (const float*)Pv + sn * 1024 + q * 128;
            const float* Br = (const float*)Pv + tn * 1024 + 512 + q * 128;
#pragma unroll
            for (int i = 0; i < 16; i++) {
                f32x4 a0 = *(const f32x4*)(Ar + i * 8);
                f32x4 a1 = *(const f32x4*)(Ar + i * 8 + 4);
                f32x4 c0 = *(const f32x4*)(Br + i * 8);
                f32x4 c1 = *(const f32x4*)(Br + i * 8 + 4);
                f32x4 d0 = *(const f32x4*)(bb + i * 8);
                f32x4 d1 = *(const f32x4*)(bb + i * 8 + 4);
                short8 hv;
#pragma unroll
                for (int j = 0; j < 4; j++) {
                    hv[j]     = (short)f2bf(fmaxf(a0[j] + c0[j] + d0[j], 0.f));
                    hv[j + 4] = (short)f2bf(fmaxf(a1[j] + c1[j] + d1[j], 0.f));
                }
                int slot = (q * 16 + i) ^ (rw & 7);
                *(short8*)(hs + rw * 512 + slot * 8) = hv;
            }
        } else {
            const unsigned short* Ar = (const unsigned short*)Pv + sn * 1024 + q * 128;
            const unsigned short* Br = (const unsigned short*)Pv + tn * 1024 + 512 + q * 128;
#pragma unroll
            for (int i = 0; i < 16; i++) {
                ushort8 av = *(const ushort8*)(Ar + i * 8);
                ushort8 cv = *(const ushort8*)(Br + i * 8);
                f32x4 d0 = *(const f32x4*)(bb + i * 8);
                f32x4 d1 = *(const f32x4*)(bb + i * 8 + 4);
                short8 hv;
#pragma unroll
                for (int j = 0; j < 4; j++) {
                    hv[j]     = (short)f2bf(fmaxf(bf2f(av[j]) + bf2f(cv[j]) + d0[j], 0.f));
                    hv[j + 4] = (short)f2bf(fmaxf(bf2f(av[j + 4]) + bf2f(cv[j + 4]) + d1[j], 0.f));
                }
                int slot = (q * 16 + i) ^ (rw & 7);
                *(short8*)(hs + rw * 512 + slot * 8) = hv;
            }
        }
    }
    __syncthreads();

    // ---- GEMM2: out[64x256] = hs[64x512] @ W2; wave w covers cols w*64 ----
    f32x4 oacc[4][4];
#pragma unroll
    for (int rt = 0; rt < 4; rt++)
#pragma unroll
        for (int ct = 0; ct < 4; ct++) oacc[rt][ct] = (f32x4){0.f, 0.f, 0.f, 0.f};

    short8 ap[2][4], bp[2][4];
    auto loadA2 = [&](short8* d, int ks) {
#pragma unroll
        for (int rt = 0; rt < 4; rt++) {
            int m = rt * 16 + lo;
            int c = (ks * 4 + quad) ^ (m & 7);
            d[rt] = *(const short8*)(hs + m * 512 + c * 8);
        }
    };
    auto loadB2 = [&](short8* d, int ks) {
#pragma unroll
        for (int ct = 0; ct < 4; ct++) {
            int ctg = w * 4 + ct;
            d[ct] = *(const short8*)(W2p + ((long)(ctg * 16 + ks) * 64 + lane) * 8);
        }
    };
    loadA2(ap[0], 0);
    loadB2(bp[0], 0);
#pragma unroll
    for (int ks = 0; ks < 16; ks++) {
        int cur = ks & 1, nxt = cur ^ 1;
        if (ks < 15) { loadA2(ap[nxt], ks + 1); loadB2(bp[nxt], ks + 1); }
#pragma unroll
        for (int ct = 0; ct < 4; ct++)
#pragma unroll
            for (int rt = 0; rt < 4; rt++)
                oacc[rt][ct] = __builtin_amdgcn_mfma_f32_16x16x32_bf16(
                    ap[cur][rt], bp[cur][ct], oacc[rt][ct], 0, 0, 0);
    }

    float bv[4];
#pragma unroll
    for (int ct = 0; ct < 4; ct++) bv[ct] = b2[w * 64 + ct * 16 + lo];
#pragma unroll
    for (int rt = 0; rt < 4; rt++) {
#pragma unroll
        for (int rr = 0; rr < 4; rr++) {
            int rwo = rt * 16 + quad * 4 + rr;
            float* op = out + (e0 + rwo) * DOUT + w * 64 + lo;
#pragma unroll
            for (int ct = 0; ct < 4; ct++)
                op[ct * 16] = oacc[rt][ct][rr] + bv[ct];
        }
    }
}

// ================= FALLBACK: previous verified fused kernel (small ws) ==========
__global__ __launch_bounds__(256, 2)
void edge_mlp(const unsigned short* __restrict__ xb,
              const int* __restrict__ eidx,
              const float* __restrict__ b1,
              const unsigned short* __restrict__ W1p,
              const float* __restrict__ b2v_g,
              const unsigned short* __restrict__ W2p,
              const int* __restrict__ flag,
              float* __restrict__ out)
{
    __shared__ unsigned short ef[M_TILE * 512];  // 49152 B
    __shared__ unsigned short hb[M_TILE * 128];  // 12288 B

    const int tid = threadIdx.x;
    const int lane = tid & 63;
    const int w = tid >> 6;
    const int lo = lane & 15;
    const int quad = lane >> 4;
    const long e0 = (long)blockIdx.x * M_TILE;
    const bool is64 = (*flag != 0);

#pragma unroll
    for (int i = 0; i < 12; i++) {
        int r = i * 4 + w;
        long e = e0 + r;
        long ec = (e < E_TOTAL) ? e : 0;
        long sn, tn;
        if (is64) {
            sn = ((const long long*)eidx)[ec];
            tn = ((const long long*)eidx)[E_TOTAL + ec];
        } else {
            sn = eidx[ec];
            tn = eidx[E_TOTAL + ec];
        }
        long node = (lane < 32) ? sn : tn;
        int cih = (lane & 31) ^ (r & 7);
        const unsigned short* g = xb + node * DIN + cih * 8;
        unsigned roff = __builtin_amdgcn_readfirstlane((unsigned)(r * 512));
        __builtin_amdgcn_global_load_lds(
            (const __attribute__((address_space(1))) void*)g,
            (__attribute__((address_space(3))) void*)(ef + roff),
            16, 0, 0);
    }
    __syncthreads();

    f32x4 oacc[3][4];
#pragma unroll
    for (int rt = 0; rt < 3; rt++)
#pragma unroll
        for (int ct = 0; ct < 4; ct++)
            oacc[rt][ct] = (f32x4){0.f, 0.f, 0.f, 0.f};

    auto loadA1 = [&](short8* dst, int ks) {
#pragma unroll
        for (int rt = 0; rt < 3; rt++) {
            int m = rt * 16 + lo;
            int c = (ks * 4 + quad) ^ (m & 7);
            dst[rt] = *(const short8*)(ef + m * 512 + c * 8);
        }
    };

    for (int kc = 0; kc < 4; kc++) {
        short8 w2f[16];
#pragma unroll
        for (int s = 0; s < 4; s++)
#pragma unroll
            for (int ct = 0; ct < 4; ct++) {
                int ctg = w * 4 + ct;
                int ks2 = kc * 4 + s;
                w2f[s * 4 + ct] =
                    *(const short8*)(W2p + ((long)(ctg * 16 + ks2) * 64 + lane) * 8);
            }
        float b1v[2];
#pragma unroll
        for (int ct = 0; ct < 2; ct++) b1v[ct] = b1[kc * 128 + w * 32 + ct * 16 + lo];

        f32x4 hacc[3][2];
#pragma unroll
        for (int rt = 0; rt < 3; rt++)
#pragma unroll
            for (int ct = 0; ct < 2; ct++)
                hacc[rt][ct] = (f32x4){0.f, 0.f, 0.f, 0.f};

        short8 a_p[2][3], b_p[2][2];
        loadA1(a_p[0], 0);
#pragma unroll
        for (int ct = 0; ct < 2; ct++) {
            int ctg = kc * 8 + w * 2 + ct;
            b_p[0][ct] = *(const short8*)(W1p + ((long)(ctg * 16 + 0) * 64 + lane) * 8);
        }

#pragma unroll
        for (int ks = 0; ks < 16; ks++) {
            int cur = ks & 1, nxt = cur ^ 1;
            if (ks < 15) {
                loadA1(a_p[nxt], ks + 1);
#pragma unroll
                for (int ct = 0; ct < 2; ct++) {
                    int ctg = kc * 8 + w * 2 + ct;
                    b_p[nxt][ct] =
                        *(const short8*)(W1p + ((long)(ctg * 16 + ks + 1) * 64 + lane) * 8);
                }
            }
#pragma unroll
            for (int ct = 0; ct < 2; ct++)
#pragma unroll
                for (int rt = 0; rt < 3; rt++)
                    hacc[rt][ct] = __builtin_amdgcn_mfma_f32_16x16x32_bf16(
                        a_p[cur][rt], b_p[cur][ct], hacc[rt][ct], 0, 0, 0);
        }

#pragma unroll
        for (int ct = 0; ct < 2; ct++) {
            int cwl = w * 32 + ct * 16 + lo;
            float bias = b1v[ct];
            int c = cwl >> 3;
            int cb = cwl & 7;
#pragma unroll
            for (int rt = 0; rt < 3; rt++) {
#pragma unroll
                for (int rr = 0; rr < 4; rr++) {
                    int rw = rt * 16 + quad * 4 + rr;
                    float v = fmaxf(hacc[rt][ct][rr] + bias, 0.f);
                    hb[rw * 128 + ((c ^ (rw & 7)) << 3) + cb] = f2bf(v);
                }
            }
        }
        __syncthreads();

        short8 a2_p[2][3];
#pragma unroll
        for (int rt = 0; rt < 3; rt++) {
            int m = rt * 16 + lo;
            int c = (0 + quad) ^ (m & 7);
            a2_p[0][rt] = *(const short8*)(hb + m * 128 + c * 8);
        }
#pragma unroll
        for (int s = 0; s < 4; s++) {
            int cur = s & 1, nxt = cur ^ 1;
            if (s < 3) {
#pragma unroll
                for (int rt = 0; rt < 3; rt++) {
                    int m = rt * 16 + lo;
                    int c = ((s + 1) * 4 + quad) ^ (m & 7);
                    a2_p[nxt][rt] = *(const short8*)(hb + m * 128 + c * 8);
                }
            }
#pragma unroll
            for (int ct = 0; ct < 4; ct++)
#pragma unroll
                for (int rt = 0; rt < 3; rt++)
                    oacc[rt][ct] = __builtin_amdgcn_mfma_f32_16x16x32_bf16(
                        a2_p[cur][rt], w2f[s * 4 + ct], oacc[rt][ct], 0, 0, 0);
        }
        if (kc < 3) __syncthreads();
    }

    float bv[4];
#pragma unroll
    for (int ct = 0; ct < 4; ct++) bv[ct] = b2v_g[w * 64 + ct * 16 + lo];
#pragma unroll
    for (int rt = 0; rt < 3; rt++) {
#pragma unroll
        for (int rr = 0; rr < 4; rr++) {
            int rw = rt * 16 + quad * 4 + rr;
            long e = e0 + rw;
            if (e < E_TOTAL) {
                float* op = out + e * DOUT + w * 64 + lo;
#pragma unroll
                for (int ct = 0; ct < 4; ct++)
                    op[ct * 16] = oacc[rt][ct][rr] + bv[ct];
            }
        }
    }
}

extern "C" void kernel_launch(void* const* d_in, const int* in_sizes, int n_in,
                              void* d_out, int out_size, void* d_ws, size_t ws_size,
                              hipStream_t stream) {
    const float* x   = (const float*)d_in[0];
    const int*   ei  = (const int*)d_in[1];
    const float* W1  = (const float*)d_in[2];
    const float* b1  = (const float*)d_in[3];
    const float* W2  = (const float*)d_in[4];
    const float* b2  = (const float*)d_in[5];
    float* out = (float*)d_out;

    // workspace layout (bytes):
    //   xb   5,120,000
    //   Wcp/W1p 524,288  @ 5,120,000
    //   W2p     262,144  @ 5,644,288
    //   flag         64  @ 5,906,432
    //   P           ...  @ 5,906,496  (fp32: 40,960,000 | bf16: 20,480,000)
    unsigned short* xb  = (unsigned short*)d_ws;
    unsigned short* Wcp = (unsigned short*)((char*)d_ws + 5120000);
    unsigned short* W2p = (unsigned short*)((char*)d_ws + 5644288);
    int* flag = (int*)((char*)d_ws + 5906432);
    void* P = (void*)((char*)d_ws + 5906496);
    const size_t NEED_F32  = 5906496ull + 40960000ull;
    const size_t NEED_BF16 = 5906496ull + 20480000ull;

    hipLaunchKernelGGL(detect_i64, dim3(1), dim3(256), 0, stream, ei, flag);
    hipLaunchKernelGGL(convert_x, dim3(1024), dim3(256), 0, stream, x, xb);
    hipLaunchKernelGGL(pack_w, dim3(64), dim3(256), 0, stream, W2, W2p, DOUT, 16, 16);

    if (ws_size >= NEED_F32) {
        hipLaunchKernelGGL(pack_wcat, dim3(128), dim3(256), 0, stream, W1, Wcp);
        hipLaunchKernelGGL((node_gemm<true>), dim3(157, 4), dim3(256), 0, stream, xb, Wcp, P);
        hipLaunchKernelGGL((edge_out<true>), dim3(5000), dim3(256), 0, stream,
                           P, ei, b1, W2p, b2, flag, out);
    } else if (ws_size >= NEED_BF16) {
        hipLaunchKernelGGL(pack_wcat, dim3(128), dim3(256), 0, stream, W1, Wcp);
        hipLaunchKernelGGL((node_gemm<false>), dim3(157, 4), dim3(256), 0, stream, xb, Wcp, P);
        hipLaunchKernelGGL((edge_out<false>), dim3(5000), dim3(256), 0, stream,
                           P, ei, b1, W2p, b2, flag, out);
    } else {
        // workspace too small for P: previous verified fused kernel
        hipLaunchKernelGGL(pack_w, dim3(128), dim3(256), 0, stream, W1, Wcp, HDIM, 32, 16);
        hipLaunchKernelGGL(edge_mlp, dim3(N_MAIN_BLOCKS), dim3(256), 0, stream,
                           xb, ei, b1, Wcp, b2, W2p, flag, out);
    }
}

// Round 3
// 565.148 us; speedup vs baseline: 1.2124x; 1.2011x over previous
//
#include <hip/hip_runtime.h>
#include <cstdint>

#define E_TOTAL 320000
#define NN 10000
#define DIN 256
#define HDIM 512
#define DOUT 256
#define M_TILE 48
#define N_MAIN_BLOCKS ((E_TOTAL + M_TILE - 1) / M_TILE)  // 6667

typedef __attribute__((ext_vector_type(8))) short short8;
typedef __attribute__((ext_vector_type(8))) unsigned short ushort8;
typedef __attribute__((ext_vector_type(4))) float f32x4;

__device__ __forceinline__ unsigned short f2bf(float f) {
    union { float f; unsigned u; } v; v.f = f;
    unsigned u = v.u;
    return (unsigned short)((u + 0x7fffu + ((u >> 16) & 1u)) >> 16);  // RNE
}
__device__ __forceinline__ float bf2f(unsigned short u) {
    union { unsigned u; float f; } v; v.u = ((unsigned)u) << 16; return v.f;
}

// ---- detect whether edge_index arrived as int64 (high dwords all zero) ----
__global__ void detect_i64(const int* __restrict__ eidx, int* __restrict__ flag) {
    __shared__ int anynz;
    if (threadIdx.x == 0) anynz = 0;
    __syncthreads();
    int v = 0;
    for (int i = threadIdx.x; i < 8192; i += blockDim.x) v |= eidx[2 * i + 1];
    if (v != 0) atomicOr(&anynz, 1);
    __syncthreads();
    if (threadIdx.x == 0) *flag = (anynz == 0) ? 1 : 0;
}

// ---- x fp32 -> bf16 ----
__global__ void convert_x(const float* __restrict__ x, unsigned short* __restrict__ xb) {
    int total = NN * DIN;
    for (int i = blockIdx.x * blockDim.x + threadIdx.x; i < total; i += gridDim.x * blockDim.x)
        xb[i] = f2bf(x[i]);
}

// ---- pack W (row-major [K][ncols] fp32) into B-fragment layout for
// mfma_f32_16x16x32_bf16: lane l holds B[k=ks*32+(l>>4)*8+j][n=ct*16+(l&15)]. ----
__global__ void pack_w(const float* __restrict__ W, unsigned short* __restrict__ Wp,
                       int ncols, int nct, int nks) {
    int tid = blockIdx.x * blockDim.x + threadIdx.x;
    int total = nct * nks * 64;
    if (tid >= total) return;
    int lane = tid & 63;
    int ks = (tid >> 6) % nks;
    int ct = tid / (64 * nks);
    int k0 = ks * 32 + (lane >> 4) * 8;
    int n = ct * 16 + (lane & 15);
    short8 v;
#pragma unroll
    for (int j = 0; j < 8; j++) v[j] = (short)f2bf(W[(long)(k0 + j) * ncols + n]);
    *(short8*)(Wp + ((long)(ct * nks + ks) * 64 + lane) * 8) = v;
}

// ---- pack Wcat[256][1024]: Wcat[k][j] = (j<512) ? W1[k][j] : W1[256+k][j-512] ----
__global__ void pack_wcat(const float* __restrict__ W1, unsigned short* __restrict__ Wp) {
    int tid = blockIdx.x * blockDim.x + threadIdx.x;
    if (tid >= 64 * 8 * 64) return;
    int lane = tid & 63;
    int ks = (tid >> 6) & 7;
    int ct = tid >> 9;                 // 0..63
    int k0 = ks * 32 + (lane >> 4) * 8;
    int n = ct * 16 + (lane & 15);     // 0..1023
    int col = n & 511;
    int radd = (n >> 9) * 256;
    short8 v;
#pragma unroll
    for (int j = 0; j < 8; j++) v[j] = (short)f2bf(W1[(long)(k0 + j + radd) * HDIM + col]);
    *(short8*)(Wp + ((long)(ct * 8 + ks) * 64 + lane) * 8) = v;
}

// ---- stage 1: P[10000][1024] = xb @ Wcat (fp32 or bf16 store) ----
template<bool PF32>
__global__ __launch_bounds__(256, 2)
void node_gemm(const unsigned short* __restrict__ xb,
               const unsigned short* __restrict__ Wcp,
               void* __restrict__ Pv)
{
    __shared__ unsigned short xs[64 * 256];  // 32 KiB, XOR-swizzled 16B chunks
    const int tid = threadIdx.x;
    const int lane = tid & 63;
    const int w = tid >> 6;
    const int lo = lane & 15;
    const int quad = lane >> 4;
    const int rt0 = blockIdx.x;
    const int cq = blockIdx.y;

#pragma unroll
    for (int i = 0; i < 8; i++) {
        int rp = i * 4 + w;
        int r = rp * 2 + (lane >> 5);
        int node = rt0 * 64 + r;
        if (node > NN - 1) node = NN - 1;
        int cs = (lane & 31) ^ (r & 7);
        const unsigned short* g = xb + (long)node * DIN + cs * 8;
        unsigned roff = __builtin_amdgcn_readfirstlane((unsigned)(rp * 512));
        __builtin_amdgcn_global_load_lds(
            (const __attribute__((address_space(1))) void*)g,
            (__attribute__((address_space(3))) void*)(xs + roff),
            16, 0, 0);
    }
    __syncthreads();

    f32x4 acc[4][4];
#pragma unroll
    for (int rt = 0; rt < 4; rt++)
#pragma unroll
        for (int ct = 0; ct < 4; ct++) acc[rt][ct] = (f32x4){0.f, 0.f, 0.f, 0.f};

    short8 ap[2][4], bp[2][4];
    auto loadA = [&](short8* d, int ks) {
#pragma unroll
        for (int rt = 0; rt < 4; rt++) {
            int m = rt * 16 + lo;
            int c = (ks * 4 + quad) ^ (m & 7);
            d[rt] = *(const short8*)(xs + m * 256 + c * 8);
        }
    };
    auto loadB = [&](short8* d, int ks) {
#pragma unroll
        for (int ct = 0; ct < 4; ct++) {
            int ctg = cq * 16 + w * 4 + ct;
            d[ct] = *(const short8*)(Wcp + ((long)(ctg * 8 + ks) * 64 + lane) * 8);
        }
    };
    loadA(ap[0], 0);
    loadB(bp[0], 0);
#pragma unroll
    for (int ks = 0; ks < 8; ks++) {
        int cur = ks & 1, nxt = cur ^ 1;
        if (ks < 7) { loadA(ap[nxt], ks + 1); loadB(bp[nxt], ks + 1); }
#pragma unroll
        for (int ct = 0; ct < 4; ct++)
#pragma unroll
            for (int rt = 0; rt < 4; rt++)
                acc[rt][ct] = __builtin_amdgcn_mfma_f32_16x16x32_bf16(
                    ap[cur][rt], bp[cur][ct], acc[rt][ct], 0, 0, 0);
    }

#pragma unroll
    for (int rt = 0; rt < 4; rt++) {
#pragma unroll
        for (int rr = 0; rr < 4; rr++) {
            int r = rt0 * 64 + rt * 16 + quad * 4 + rr;
            if (r < NN) {
                long off = (long)r * 1024 + cq * 256 + w * 64 + lo;
#pragma unroll
                for (int ct = 0; ct < 4; ct++) {
                    float v = acc[rt][ct][rr];
                    if constexpr (PF32) ((float*)Pv)[off + ct * 16] = v;
                    else ((unsigned short*)Pv)[off + ct * 16] = f2bf(v);
                }
            }
        }
    }
}

// ---- stage 2 v2: 512 threads (8 waves), 64 edges/block.
// Gather is FEATURE-PARALLEL: per edge, lane l covers features l*8..l*8+7
// (coalesced 16B loads across the wave), one ds_write_b128 per edge per lane.
// GEMM2 col-split 8 ways: wave w computes cols w*32..w*32+31 over all 64 rows.
template<bool PF32>
__global__ __launch_bounds__(512, 4)
void edge_out(const void* __restrict__ Pv,
              const int* __restrict__ eidx,
              const float* __restrict__ b1,
              const unsigned short* __restrict__ W2p,
              const float* __restrict__ b2,
              const int* __restrict__ flag,
              float* __restrict__ out)
{
    __shared__ unsigned short hs[64 * 512];  // 64 KiB, XOR-swizzled 16B chunks
    const int tid = threadIdx.x;
    const int lane = tid & 63;
    const int w = tid >> 6;          // 0..7
    const int lo = lane & 15;
    const int quad = lane >> 4;
    const long e0 = (long)blockIdx.x * 64;

    // ---- per-lane edge-index preload: lane&7 = local edge of this wave ----
    const bool is64 = (*flag != 0);
    int snv, tnv;
    {
        long e = e0 + w * 8 + (lane & 7);
        long s, t;
        if (is64) {
            s = ((const long long*)eidx)[e];
            t = ((const long long*)eidx)[E_TOTAL + e];
        } else {
            s = eidx[e];
            t = eidx[E_TOTAL + e];
        }
        if (s < 0) s = 0; if (s > NN - 1) s = NN - 1;
        if (t < 0) t = 0; if (t > NN - 1) t = NN - 1;
        snv = (int)s; tnv = (int)t;
    }
    f32x4 bia0 = *(const f32x4*)(b1 + lane * 8);
    f32x4 bia1 = *(const f32x4*)(b1 + lane * 8 + 4);

    // ---- gather + add + bias + relu -> hs (wave w fills rows w*8..w*8+7) ----
#pragma unroll
    for (int j = 0; j < 8; j++) {
        int sv = __shfl(snv, j, 8);     // wave-uniform node ids for edge j
        int tv = __shfl(tnv, j, 8);
        int r = w * 8 + j;
        short8 hv;
        if constexpr (PF32) {
            const float* Ar = (const float*)Pv + (long)sv * 1024 + lane * 8;
            const float* Br = (const float*)Pv + (long)tv * 1024 + 512 + lane * 8;
            f32x4 a0 = *(const f32x4*)(Ar);
            f32x4 a1 = *(const f32x4*)(Ar + 4);
            f32x4 c0 = *(const f32x4*)(Br);
            f32x4 c1 = *(const f32x4*)(Br + 4);
#pragma unroll
            for (int jj = 0; jj < 4; jj++) {
                hv[jj]     = (short)f2bf(fmaxf(a0[jj] + c0[jj] + bia0[jj], 0.f));
                hv[jj + 4] = (short)f2bf(fmaxf(a1[jj] + c1[jj] + bia1[jj], 0.f));
            }
        } else {
            const unsigned short* Ar = (const unsigned short*)Pv + (long)sv * 1024 + lane * 8;
            const unsigned short* Br = (const unsigned short*)Pv + (long)tv * 1024 + 512 + lane * 8;
            ushort8 av = *(const ushort8*)(Ar);
            ushort8 cv = *(const ushort8*)(Br);
#pragma unroll
            for (int jj = 0; jj < 4; jj++) {
                hv[jj]     = (short)f2bf(fmaxf(bf2f(av[jj]) + bf2f(cv[jj]) + bia0[jj], 0.f));
                hv[jj + 4] = (short)f2bf(fmaxf(bf2f(av[jj + 4]) + bf2f(cv[jj + 4]) + bia1[jj], 0.f));
            }
        }
        // chunk c = lane (feature block), XOR-swizzled by row
        *(short8*)(hs + r * 512 + ((lane ^ (r & 7)) << 3)) = hv;
    }
    __syncthreads();

    // ---- GEMM2: out[64x256] = hs[64x512] @ W2; wave w covers cols w*32 ----
    f32x4 oacc[4][2];
#pragma unroll
    for (int rt = 0; rt < 4; rt++)
#pragma unroll
        for (int ct = 0; ct < 2; ct++) oacc[rt][ct] = (f32x4){0.f, 0.f, 0.f, 0.f};

    short8 ap[2][4], bp[2][2];
    auto loadA2 = [&](short8* d, int ks) {
#pragma unroll
        for (int rt = 0; rt < 4; rt++) {
            int m = rt * 16 + lo;
            int c = (ks * 4 + quad) ^ (m & 7);
            d[rt] = *(const short8*)(hs + m * 512 + c * 8);
        }
    };
    auto loadB2 = [&](short8* d, int ks) {
#pragma unroll
        for (int ct = 0; ct < 2; ct++) {
            int ctg = w * 2 + ct;
            d[ct] = *(const short8*)(W2p + ((long)(ctg * 16 + ks) * 64 + lane) * 8);
        }
    };
    loadA2(ap[0], 0);
    loadB2(bp[0], 0);
#pragma unroll
    for (int ks = 0; ks < 16; ks++) {
        int cur = ks & 1, nxt = cur ^ 1;
        if (ks < 15) { loadA2(ap[nxt], ks + 1); loadB2(bp[nxt], ks + 1); }
#pragma unroll
        for (int ct = 0; ct < 2; ct++)
#pragma unroll
            for (int rt = 0; rt < 4; rt++)
                oacc[rt][ct] = __builtin_amdgcn_mfma_f32_16x16x32_bf16(
                    ap[cur][rt], bp[cur][ct], oacc[rt][ct], 0, 0, 0);
    }

    // ---- epilogue: +b2, store fp32 ----
    float bv[2];
#pragma unroll
    for (int ct = 0; ct < 2; ct++) bv[ct] = b2[w * 32 + ct * 16 + lo];
#pragma unroll
    for (int rt = 0; rt < 4; rt++) {
#pragma unroll
        for (int rr = 0; rr < 4; rr++) {
            int rwo = rt * 16 + quad * 4 + rr;
            float* op = out + (e0 + rwo) * DOUT + w * 32 + lo;
#pragma unroll
            for (int ct = 0; ct < 2; ct++)
                op[ct * 16] = oacc[rt][ct][rr] + bv[ct];
        }
    }
}

// ================= FALLBACK: previous verified fused kernel (small ws) ==========
__global__ __launch_bounds__(256, 2)
void edge_mlp(const unsigned short* __restrict__ xb,
              const int* __restrict__ eidx,
              const float* __restrict__ b1,
              const unsigned short* __restrict__ W1p,
              const float* __restrict__ b2v_g,
              const unsigned short* __restrict__ W2p,
              const int* __restrict__ flag,
              float* __restrict__ out)
{
    __shared__ unsigned short ef[M_TILE * 512];
    __shared__ unsigned short hb[M_TILE * 128];

    const int tid = threadIdx.x;
    const int lane = tid & 63;
    const int w = tid >> 6;
    const int lo = lane & 15;
    const int quad = lane >> 4;
    const long e0 = (long)blockIdx.x * M_TILE;
    const bool is64 = (*flag != 0);

#pragma unroll
    for (int i = 0; i < 12; i++) {
        int r = i * 4 + w;
        long e = e0 + r;
        long ec = (e < E_TOTAL) ? e : 0;
        long sn, tn;
        if (is64) {
            sn = ((const long long*)eidx)[ec];
            tn = ((const long long*)eidx)[E_TOTAL + ec];
        } else {
            sn = eidx[ec];
            tn = eidx[E_TOTAL + ec];
        }
        long node = (lane < 32) ? sn : tn;
        int cih = (lane & 31) ^ (r & 7);
        const unsigned short* g = xb + node * DIN + cih * 8;
        unsigned roff = __builtin_amdgcn_readfirstlane((unsigned)(r * 512));
        __builtin_amdgcn_global_load_lds(
            (const __attribute__((address_space(1))) void*)g,
            (__attribute__((address_space(3))) void*)(ef + roff),
            16, 0, 0);
    }
    __syncthreads();

    f32x4 oacc[3][4];
#pragma unroll
    for (int rt = 0; rt < 3; rt++)
#pragma unroll
        for (int ct = 0; ct < 4; ct++)
            oacc[rt][ct] = (f32x4){0.f, 0.f, 0.f, 0.f};

    auto loadA1 = [&](short8* dst, int ks) {
#pragma unroll
        for (int rt = 0; rt < 3; rt++) {
            int m = rt * 16 + lo;
            int c = (ks * 4 + quad) ^ (m & 7);
            dst[rt] = *(const short8*)(ef + m * 512 + c * 8);
        }
    };

    for (int kc = 0; kc < 4; kc++) {
        short8 w2f[16];
#pragma unroll
        for (int s = 0; s < 4; s++)
#pragma unroll
            for (int ct = 0; ct < 4; ct++) {
                int ctg = w * 4 + ct;
                int ks2 = kc * 4 + s;
                w2f[s * 4 + ct] =
                    *(const short8*)(W2p + ((long)(ctg * 16 + ks2) * 64 + lane) * 8);
            }
        float b1v[2];
#pragma unroll
        for (int ct = 0; ct < 2; ct++) b1v[ct] = b1[kc * 128 + w * 32 + ct * 16 + lo];

        f32x4 hacc[3][2];
#pragma unroll
        for (int rt = 0; rt < 3; rt++)
#pragma unroll
            for (int ct = 0; ct < 2; ct++)
                hacc[rt][ct] = (f32x4){0.f, 0.f, 0.f, 0.f};

        short8 a_p[2][3], b_p[2][2];
        loadA1(a_p[0], 0);
#pragma unroll
        for (int ct = 0; ct < 2; ct++) {
            int ctg = kc * 8 + w * 2 + ct;
            b_p[0][ct] = *(const short8*)(W1p + ((long)(ctg * 16 + 0) * 64 + lane) * 8);
        }

#pragma unroll
        for (int ks = 0; ks < 16; ks++) {
            int cur = ks & 1, nxt = cur ^ 1;
            if (ks < 15) {
                loadA1(a_p[nxt], ks + 1);
#pragma unroll
                for (int ct = 0; ct < 2; ct++) {
                    int ctg = kc * 8 + w * 2 + ct;
                    b_p[nxt][ct] =
                        *(const short8*)(W1p + ((long)(ctg * 16 + ks + 1) * 64 + lane) * 8);
                }
            }
#pragma unroll
            for (int ct = 0; ct < 2; ct++)
#pragma unroll
                for (int rt = 0; rt < 3; rt++)
                    hacc[rt][ct] = __builtin_amdgcn_mfma_f32_16x16x32_bf16(
                        a_p[cur][rt], b_p[cur][ct], hacc[rt][ct], 0, 0, 0);
        }

#pragma unroll
        for (int ct = 0; ct < 2; ct++) {
            int cwl = w * 32 + ct * 16 + lo;
            float bias = b1v[ct];
            int c = cwl >> 3;
            int cb = cwl & 7;
#pragma unroll
            for (int rt = 0; rt < 3; rt++) {
#pragma unroll
                for (int rr = 0; rr < 4; rr++) {
                    int rw = rt * 16 + quad * 4 + rr;
                    float v = fmaxf(hacc[rt][ct][rr] + bias, 0.f);
                    hb[rw * 128 + ((c ^ (rw & 7)) << 3) + cb] = f2bf(v);
                }
            }
        }
        __syncthreads();

        short8 a2_p[2][3];
#pragma unroll
        for (int rt = 0; rt < 3; rt++) {
            int m = rt * 16 + lo;
            int c = (0 + quad) ^ (m & 7);
            a2_p[0][rt] = *(const short8*)(hb + m * 128 + c * 8);
        }
#pragma unroll
        for (int s = 0; s < 4; s++) {
            int cur = s & 1, nxt = cur ^ 1;
            if (s < 3) {
#pragma unroll
                for (int rt = 0; rt < 3; rt++) {
                    int m = rt * 16 + lo;
                    int c = ((s + 1) * 4 + quad) ^ (m & 7);
                    a2_p[nxt][rt] = *(const short8*)(hb + m * 128 + c * 8);
                }
            }
#pragma unroll
            for (int ct = 0; ct < 4; ct++)
#pragma unroll
                for (int rt = 0; rt < 3; rt++)
                    oacc[rt][ct] = __builtin_amdgcn_mfma_f32_16x16x32_bf16(
                        a2_p[cur][rt], w2f[s * 4 + ct], oacc[rt][ct], 0, 0, 0);
        }
        if (kc < 3) __syncthreads();
    }

    float bv[4];
#pragma unroll
    for (int ct = 0; ct < 4; ct++) bv[ct] = b2v_g[w * 64 + ct * 16 + lo];
#pragma unroll
    for (int rt = 0; rt < 3; rt++) {
#pragma unroll
        for (int rr = 0; rr < 4; rr++) {
            int rw = rt * 16 + quad * 4 + rr;
            long e = e0 + rw;
            if (e < E_TOTAL) {
                float* op = out + e * DOUT + w * 64 + lo;
#pragma unroll
                for (int ct = 0; ct < 4; ct++)
                    op[ct * 16] = oacc[rt][ct][rr] + bv[ct];
            }
        }
    }
}

extern "C" void kernel_launch(void* const* d_in, const int* in_sizes, int n_in,
                              void* d_out, int out_size, void* d_ws, size_t ws_size,
                              hipStream_t stream) {
    const float* x   = (const float*)d_in[0];
    const int*   ei  = (const int*)d_in[1];
    const float* W1  = (const float*)d_in[2];
    const float* b1  = (const float*)d_in[3];
    const float* W2  = (const float*)d_in[4];
    const float* b2  = (const float*)d_in[5];
    float* out = (float*)d_out;

    // workspace layout (bytes):
    //   xb   5,120,000
    //   Wcp/W1p 524,288  @ 5,120,000
    //   W2p     262,144  @ 5,644,288
    //   flag         64  @ 5,906,432
    //   P           ...  @ 5,906,496  (fp32: 40,960,000 | bf16: 20,480,000)
    unsigned short* xb  = (unsigned short*)d_ws;
    unsigned short* Wcp = (unsigned short*)((char*)d_ws + 5120000);
    unsigned short* W2p = (unsigned short*)((char*)d_ws + 5644288);
    int* flag = (int*)((char*)d_ws + 5906432);
    void* P = (void*)((char*)d_ws + 5906496);
    const size_t NEED_F32  = 5906496ull + 40960000ull;
    const size_t NEED_BF16 = 5906496ull + 20480000ull;

    hipLaunchKernelGGL(detect_i64, dim3(1), dim3(256), 0, stream, ei, flag);
    hipLaunchKernelGGL(convert_x, dim3(1024), dim3(256), 0, stream, x, xb);
    hipLaunchKernelGGL(pack_w, dim3(64), dim3(256), 0, stream, W2, W2p, DOUT, 16, 16);

    if (ws_size >= NEED_F32) {
        hipLaunchKernelGGL(pack_wcat, dim3(128), dim3(256), 0, stream, W1, Wcp);
        hipLaunchKernelGGL((node_gemm<true>), dim3(157, 4), dim3(256), 0, stream, xb, Wcp, P);
        hipLaunchKernelGGL((edge_out<true>), dim3(5000), dim3(512), 0, stream,
                           P, ei, b1, W2p, b2, flag, out);
    } else if (ws_size >= NEED_BF16) {
        hipLaunchKernelGGL(pack_wcat, dim3(128), dim3(256), 0, stream, W1, Wcp);
        hipLaunchKernelGGL((node_gemm<false>), dim3(157, 4), dim3(256), 0, stream, xb, Wcp, P);
        hipLaunchKernelGGL((edge_out<false>), dim3(5000), dim3(512), 0, stream,
                           P, ei, b1, W2p, b2, flag, out);
    } else {
        hipLaunchKernelGGL(pack_w, dim3(128), dim3(256), 0, stream, W1, Wcp, HDIM, 32, 16);
        hipLaunchKernelGGL(edge_mlp, dim3(N_MAIN_BLOCKS), dim3(256), 0, stream,
                           xb, ei, b1, Wcp, b2, W2p, flag, out);
    }
}

// Round 4
// 467.887 us; speedup vs baseline: 1.4645x; 1.2079x over previous
//
#include <hip/hip_runtime.h>
#include <cstdint>

#define E_TOTAL 320000
#define NN 10000
#define DIN 256
#define HDIM 512
#define DOUT 256
#define M_TILE 48
#define N_MAIN_BLOCKS ((E_TOTAL + M_TILE - 1) / M_TILE)  // 6667

typedef __attribute__((ext_vector_type(8))) short short8;
typedef __attribute__((ext_vector_type(8))) unsigned short ushort8;
typedef __attribute__((ext_vector_type(4))) float f32x4;

__device__ __forceinline__ unsigned short f2bf(float f) {
    union { float f; unsigned u; } v; v.f = f;
    unsigned u = v.u;
    return (unsigned short)((u + 0x7fffu + ((u >> 16) & 1u)) >> 16);  // RNE
}
__device__ __forceinline__ float bf2f(unsigned short u) {
    union { unsigned u; float f; } v; v.u = ((unsigned)u) << 16; return v.f;
}

// ---- detect whether edge_index arrived as int64 (high dwords all zero) ----
__global__ void detect_i64(const int* __restrict__ eidx, int* __restrict__ flag) {
    __shared__ int anynz;
    if (threadIdx.x == 0) anynz = 0;
    __syncthreads();
    int v = 0;
    for (int i = threadIdx.x; i < 8192; i += blockDim.x) v |= eidx[2 * i + 1];
    if (v != 0) atomicOr(&anynz, 1);
    __syncthreads();
    if (threadIdx.x == 0) *flag = (anynz == 0) ? 1 : 0;
}

// ---- x fp32 -> bf16 ----
__global__ void convert_x(const float* __restrict__ x, unsigned short* __restrict__ xb) {
    int total = NN * DIN;
    for (int i = blockIdx.x * blockDim.x + threadIdx.x; i < total; i += gridDim.x * blockDim.x)
        xb[i] = f2bf(x[i]);
}

// ---- pack W (row-major [K][ncols] fp32) into B-fragment layout for
// mfma_f32_16x16x32_bf16: lane l holds B[k=ks*32+(l>>4)*8+j][n=ct*16+(l&15)]. ----
__global__ void pack_w(const float* __restrict__ W, unsigned short* __restrict__ Wp,
                       int ncols, int nct, int nks) {
    int tid = blockIdx.x * blockDim.x + threadIdx.x;
    int total = nct * nks * 64;
    if (tid >= total) return;
    int lane = tid & 63;
    int ks = (tid >> 6) % nks;
    int ct = tid / (64 * nks);
    int k0 = ks * 32 + (lane >> 4) * 8;
    int n = ct * 16 + (lane & 15);
    short8 v;
#pragma unroll
    for (int j = 0; j < 8; j++) v[j] = (short)f2bf(W[(long)(k0 + j) * ncols + n]);
    *(short8*)(Wp + ((long)(ct * nks + ks) * 64 + lane) * 8) = v;
}

// ---- pack Wcat[256][1024]: Wcat[k][j] = (j<512) ? W1[k][j] : W1[256+k][j-512] ----
__global__ void pack_wcat(const float* __restrict__ W1, unsigned short* __restrict__ Wp) {
    int tid = blockIdx.x * blockDim.x + threadIdx.x;
    if (tid >= 64 * 8 * 64) return;
    int lane = tid & 63;
    int ks = (tid >> 6) & 7;
    int ct = tid >> 9;                 // 0..63
    int k0 = ks * 32 + (lane >> 4) * 8;
    int n = ct * 16 + (lane & 15);     // 0..1023
    int col = n & 511;
    int radd = (n >> 9) * 256;
    short8 v;
#pragma unroll
    for (int j = 0; j < 8; j++) v[j] = (short)f2bf(W1[(long)(k0 + j + radd) * HDIM + col]);
    *(short8*)(Wp + ((long)(ct * 8 + ks) * 64 + lane) * 8) = v;
}

// ---- stage 1: P[10000][1024] = xb @ Wcat (fp32 or bf16 store) ----
template<bool PF32>
__global__ __launch_bounds__(256, 2)
void node_gemm(const unsigned short* __restrict__ xb,
               const unsigned short* __restrict__ Wcp,
               void* __restrict__ Pv)
{
    __shared__ unsigned short xs[64 * 256];  // 32 KiB, XOR-swizzled 16B chunks
    const int tid = threadIdx.x;
    const int lane = tid & 63;
    const int w = tid >> 6;
    const int lo = lane & 15;
    const int quad = lane >> 4;
    const int rt0 = blockIdx.x;
    const int cq = blockIdx.y;

#pragma unroll
    for (int i = 0; i < 8; i++) {
        int rp = i * 4 + w;
        int r = rp * 2 + (lane >> 5);
        int node = rt0 * 64 + r;
        if (node > NN - 1) node = NN - 1;
        int cs = (lane & 31) ^ (r & 7);
        const unsigned short* g = xb + (long)node * DIN + cs * 8;
        unsigned roff = __builtin_amdgcn_readfirstlane((unsigned)(rp * 512));
        __builtin_amdgcn_global_load_lds(
            (const __attribute__((address_space(1))) void*)g,
            (__attribute__((address_space(3))) void*)(xs + roff),
            16, 0, 0);
    }
    __syncthreads();

    f32x4 acc[4][4];
#pragma unroll
    for (int rt = 0; rt < 4; rt++)
#pragma unroll
        for (int ct = 0; ct < 4; ct++) acc[rt][ct] = (f32x4){0.f, 0.f, 0.f, 0.f};

    short8 ap[2][4], bp[2][4];
    auto loadA = [&](short8* d, int ks) {
#pragma unroll
        for (int rt = 0; rt < 4; rt++) {
            int m = rt * 16 + lo;
            int c = (ks * 4 + quad) ^ (m & 7);
            d[rt] = *(const short8*)(xs + m * 256 + c * 8);
        }
    };
    auto loadB = [&](short8* d, int ks) {
#pragma unroll
        for (int ct = 0; ct < 4; ct++) {
            int ctg = cq * 16 + w * 4 + ct;
            d[ct] = *(const short8*)(Wcp + ((long)(ctg * 8 + ks) * 64 + lane) * 8);
        }
    };
    loadA(ap[0], 0);
    loadB(bp[0], 0);
#pragma unroll
    for (int ks = 0; ks < 8; ks++) {
        int cur = ks & 1, nxt = cur ^ 1;
        if (ks < 7) { loadA(ap[nxt], ks + 1); loadB(bp[nxt], ks + 1); }
#pragma unroll
        for (int ct = 0; ct < 4; ct++)
#pragma unroll
            for (int rt = 0; rt < 4; rt++)
                acc[rt][ct] = __builtin_amdgcn_mfma_f32_16x16x32_bf16(
                    ap[cur][rt], bp[cur][ct], acc[rt][ct], 0, 0, 0);
    }

#pragma unroll
    for (int rt = 0; rt < 4; rt++) {
#pragma unroll
        for (int rr = 0; rr < 4; rr++) {
            int r = rt0 * 64 + rt * 16 + quad * 4 + rr;
            if (r < NN) {
                long off = (long)r * 1024 + cq * 256 + w * 64 + lo;
#pragma unroll
                for (int ct = 0; ct < 4; ct++) {
                    float v = acc[rt][ct][rr];
                    if constexpr (PF32) ((float*)Pv)[off + ct * 16] = v;
                    else ((unsigned short*)Pv)[off + ct * 16] = f2bf(v);
                }
            }
        }
    }
}

// ---- stage 2 v3: 512 threads (8 waves), 64 edges/block, bf16 P.
// Gather: feature-parallel, ALL 16 loads issued before first consume
// (static-indexed arrays -> in-flight in VGPRs, single latency exposure).
// GEMM2 col-split 8: wave w computes cols w*32..w*32+31 over all 64 rows.
template<bool PF32>
__global__ __launch_bounds__(512, 4)
void edge_out(const void* __restrict__ Pv,
              const int* __restrict__ eidx,
              const float* __restrict__ b1,
              const unsigned short* __restrict__ W2p,
              const float* __restrict__ b2,
              const int* __restrict__ flag,
              float* __restrict__ out)
{
    __shared__ unsigned short hs[64 * 512];  // 64 KiB, XOR-swizzled 16B chunks
    const int tid = threadIdx.x;
    const int lane = tid & 63;
    const int w = tid >> 6;          // 0..7
    const int lo = lane & 15;
    const int quad = lane >> 4;
    const long e0 = (long)blockIdx.x * 64;

    // ---- per-lane edge-index preload: lane&7 = local edge of this wave ----
    const bool is64 = (*flag != 0);
    int snv, tnv;
    {
        long e = e0 + w * 8 + (lane & 7);
        long s, t;
        if (is64) {
            s = ((const long long*)eidx)[e];
            t = ((const long long*)eidx)[E_TOTAL + e];
        } else {
            s = eidx[e];
            t = eidx[E_TOTAL + e];
        }
        if (s < 0) s = 0; if (s > NN - 1) s = NN - 1;
        if (t < 0) t = 0; if (t > NN - 1) t = NN - 1;
        snv = (int)s; tnv = (int)t;
    }
    f32x4 bia0 = *(const f32x4*)(b1 + lane * 8);
    f32x4 bia1 = *(const f32x4*)(b1 + lane * 8 + 4);

    // broadcast the wave's 8 edge ids to all lanes (group-of-8 shuffle)
    int svv[8], tvv[8];
#pragma unroll
    for (int j = 0; j < 8; j++) {
        svv[j] = __shfl(snv, j, 8);
        tvv[j] = __shfl(tnv, j, 8);
    }

    if constexpr (PF32) {
        // fp32-P path (kept for revert): per-edge immediate consume
#pragma unroll
        for (int j = 0; j < 8; j++) {
            int r = w * 8 + j;
            const float* Ar = (const float*)Pv + (long)svv[j] * 1024 + lane * 8;
            const float* Br = (const float*)Pv + (long)tvv[j] * 1024 + 512 + lane * 8;
            f32x4 a0 = *(const f32x4*)(Ar);
            f32x4 a1 = *(const f32x4*)(Ar + 4);
            f32x4 c0 = *(const f32x4*)(Br);
            f32x4 c1 = *(const f32x4*)(Br + 4);
            short8 hv;
#pragma unroll
            for (int jj = 0; jj < 4; jj++) {
                hv[jj]     = (short)f2bf(fmaxf(a0[jj] + c0[jj] + bia0[jj], 0.f));
                hv[jj + 4] = (short)f2bf(fmaxf(a1[jj] + c1[jj] + bia1[jj], 0.f));
            }
            *(short8*)(hs + r * 512 + ((lane ^ (r & 7)) << 3)) = hv;
        }
    } else {
        // bf16-P path: issue ALL 16 loads first (one 16B ushort8 per edge-half)
        const unsigned short* Pb = (const unsigned short*)Pv;
        ushort8 pa[8], pt[8];
#pragma unroll
        for (int j = 0; j < 8; j++) {
            pa[j] = *(const ushort8*)(Pb + (long)svv[j] * 1024 + lane * 8);
            pt[j] = *(const ushort8*)(Pb + (long)tvv[j] * 1024 + 512 + lane * 8);
        }
#pragma unroll
        for (int j = 0; j < 8; j++) {
            int r = w * 8 + j;
            short8 hv;
#pragma unroll
            for (int jj = 0; jj < 4; jj++) {
                hv[jj]     = (short)f2bf(fmaxf(bf2f(pa[j][jj]) + bf2f(pt[j][jj]) + bia0[jj], 0.f));
                hv[jj + 4] = (short)f2bf(fmaxf(bf2f(pa[j][jj + 4]) + bf2f(pt[j][jj + 4]) + bia1[jj], 0.f));
            }
            *(short8*)(hs + r * 512 + ((lane ^ (r & 7)) << 3)) = hv;
        }
    }
    __syncthreads();

    // ---- GEMM2: out[64x256] = hs[64x512] @ W2; wave w covers cols w*32 ----
    f32x4 oacc[4][2];
#pragma unroll
    for (int rt = 0; rt < 4; rt++)
#pragma unroll
        for (int ct = 0; ct < 2; ct++) oacc[rt][ct] = (f32x4){0.f, 0.f, 0.f, 0.f};

    short8 ap[2][4], bp[2][2];
    auto loadA2 = [&](short8* d, int ks) {
#pragma unroll
        for (int rt = 0; rt < 4; rt++) {
            int m = rt * 16 + lo;
            int c = (ks * 4 + quad) ^ (m & 7);
            d[rt] = *(const short8*)(hs + m * 512 + c * 8);
        }
    };
    auto loadB2 = [&](short8* d, int ks) {
#pragma unroll
        for (int ct = 0; ct < 2; ct++) {
            int ctg = w * 2 + ct;
            d[ct] = *(const short8*)(W2p + ((long)(ctg * 16 + ks) * 64 + lane) * 8);
        }
    };
    loadA2(ap[0], 0);
    loadB2(bp[0], 0);
#pragma unroll
    for (int ks = 0; ks < 16; ks++) {
        int cur = ks & 1, nxt = cur ^ 1;
        if (ks < 15) { loadA2(ap[nxt], ks + 1); loadB2(bp[nxt], ks + 1); }
#pragma unroll
        for (int ct = 0; ct < 2; ct++)
#pragma unroll
            for (int rt = 0; rt < 4; rt++)
                oacc[rt][ct] = __builtin_amdgcn_mfma_f32_16x16x32_bf16(
                    ap[cur][rt], bp[cur][ct], oacc[rt][ct], 0, 0, 0);
    }

    // ---- epilogue: +b2, nontemporal fp32 stores (out never re-read) ----
    float bv[2];
#pragma unroll
    for (int ct = 0; ct < 2; ct++) bv[ct] = b2[w * 32 + ct * 16 + lo];
#pragma unroll
    for (int rt = 0; rt < 4; rt++) {
#pragma unroll
        for (int rr = 0; rr < 4; rr++) {
            int rwo = rt * 16 + quad * 4 + rr;
            float* op = out + (e0 + rwo) * DOUT + w * 32 + lo;
#pragma unroll
            for (int ct = 0; ct < 2; ct++)
                __builtin_nontemporal_store(oacc[rt][ct][rr] + bv[ct], op + ct * 16);
        }
    }
}

// ================= FALLBACK: previous verified fused kernel (small ws) ==========
__global__ __launch_bounds__(256, 2)
void edge_mlp(const unsigned short* __restrict__ xb,
              const int* __restrict__ eidx,
              const float* __restrict__ b1,
              const unsigned short* __restrict__ W1p,
              const float* __restrict__ b2v_g,
              const unsigned short* __restrict__ W2p,
              const int* __restrict__ flag,
              float* __restrict__ out)
{
    __shared__ unsigned short ef[M_TILE * 512];
    __shared__ unsigned short hb[M_TILE * 128];

    const int tid = threadIdx.x;
    const int lane = tid & 63;
    const int w = tid >> 6;
    const int lo = lane & 15;
    const int quad = lane >> 4;
    const long e0 = (long)blockIdx.x * M_TILE;
    const bool is64 = (*flag != 0);

#pragma unroll
    for (int i = 0; i < 12; i++) {
        int r = i * 4 + w;
        long e = e0 + r;
        long ec = (e < E_TOTAL) ? e : 0;
        long sn, tn;
        if (is64) {
            sn = ((const long long*)eidx)[ec];
            tn = ((const long long*)eidx)[E_TOTAL + ec];
        } else {
            sn = eidx[ec];
            tn = eidx[E_TOTAL + ec];
        }
        long node = (lane < 32) ? sn : tn;
        int cih = (lane & 31) ^ (r & 7);
        const unsigned short* g = xb + node * DIN + cih * 8;
        unsigned roff = __builtin_amdgcn_readfirstlane((unsigned)(r * 512));
        __builtin_amdgcn_global_load_lds(
            (const __attribute__((address_space(1))) void*)g,
            (__attribute__((address_space(3))) void*)(ef + roff),
            16, 0, 0);
    }
    __syncthreads();

    f32x4 oacc[3][4];
#pragma unroll
    for (int rt = 0; rt < 3; rt++)
#pragma unroll
        for (int ct = 0; ct < 4; ct++)
            oacc[rt][ct] = (f32x4){0.f, 0.f, 0.f, 0.f};

    auto loadA1 = [&](short8* dst, int ks) {
#pragma unroll
        for (int rt = 0; rt < 3; rt++) {
            int m = rt * 16 + lo;
            int c = (ks * 4 + quad) ^ (m & 7);
            dst[rt] = *(const short8*)(ef + m * 512 + c * 8);
        }
    };

    for (int kc = 0; kc < 4; kc++) {
        short8 w2f[16];
#pragma unroll
        for (int s = 0; s < 4; s++)
#pragma unroll
            for (int ct = 0; ct < 4; ct++) {
                int ctg = w * 4 + ct;
                int ks2 = kc * 4 + s;
                w2f[s * 4 + ct] =
                    *(const short8*)(W2p + ((long)(ctg * 16 + ks2) * 64 + lane) * 8);
            }
        float b1v[2];
#pragma unroll
        for (int ct = 0; ct < 2; ct++) b1v[ct] = b1[kc * 128 + w * 32 + ct * 16 + lo];

        f32x4 hacc[3][2];
#pragma unroll
        for (int rt = 0; rt < 3; rt++)
#pragma unroll
            for (int ct = 0; ct < 2; ct++)
                hacc[rt][ct] = (f32x4){0.f, 0.f, 0.f, 0.f};

        short8 a_p[2][3], b_p[2][2];
        loadA1(a_p[0], 0);
#pragma unroll
        for (int ct = 0; ct < 2; ct++) {
            int ctg = kc * 8 + w * 2 + ct;
            b_p[0][ct] = *(const short8*)(W1p + ((long)(ctg * 16 + 0) * 64 + lane) * 8);
        }

#pragma unroll
        for (int ks = 0; ks < 16; ks++) {
            int cur = ks & 1, nxt = cur ^ 1;
            if (ks < 15) {
                loadA1(a_p[nxt], ks + 1);
#pragma unroll
                for (int ct = 0; ct < 2; ct++) {
                    int ctg = kc * 8 + w * 2 + ct;
                    b_p[nxt][ct] =
                        *(const short8*)(W1p + ((long)(ctg * 16 + ks + 1) * 64 + lane) * 8);
                }
            }
#pragma unroll
            for (int ct = 0; ct < 2; ct++)
#pragma unroll
                for (int rt = 0; rt < 3; rt++)
                    hacc[rt][ct] = __builtin_amdgcn_mfma_f32_16x16x32_bf16(
                        a_p[cur][rt], b_p[cur][ct], hacc[rt][ct], 0, 0, 0);
        }

#pragma unroll
        for (int ct = 0; ct < 2; ct++) {
            int cwl = w * 32 + ct * 16 + lo;
            float bias = b1v[ct];
            int c = cwl >> 3;
            int cb = cwl & 7;
#pragma unroll
            for (int rt = 0; rt < 3; rt++) {
#pragma unroll
                for (int rr = 0; rr < 4; rr++) {
                    int rw = rt * 16 + quad * 4 + rr;
                    float v = fmaxf(hacc[rt][ct][rr] + bias, 0.f);
                    hb[rw * 128 + ((c ^ (rw & 7)) << 3) + cb] = f2bf(v);
                }
            }
        }
        __syncthreads();

        short8 a2_p[2][3];
#pragma unroll
        for (int rt = 0; rt < 3; rt++) {
            int m = rt * 16 + lo;
            int c = (0 + quad) ^ (m & 7);
            a2_p[0][rt] = *(const short8*)(hb + m * 128 + c * 8);
        }
#pragma unroll
        for (int s = 0; s < 4; s++) {
            int cur = s & 1, nxt = cur ^ 1;
            if (s < 3) {
#pragma unroll
                for (int rt = 0; rt < 3; rt++) {
                    int m = rt * 16 + lo;
                    int c = ((s + 1) * 4 + quad) ^ (m & 7);
                    a2_p[nxt][rt] = *(const short8*)(hb + m * 128 + c * 8);
                }
            }
#pragma unroll
            for (int ct = 0; ct < 4; ct++)
#pragma unroll
                for (int rt = 0; rt < 3; rt++)
                    oacc[rt][ct] = __builtin_amdgcn_mfma_f32_16x16x32_bf16(
                        a2_p[cur][rt], w2f[s * 4 + ct], oacc[rt][ct], 0, 0, 0);
        }
        if (kc < 3) __syncthreads();
    }

    float bv[4];
#pragma unroll
    for (int ct = 0; ct < 4; ct++) bv[ct] = b2v_g[w * 64 + ct * 16 + lo];
#pragma unroll
    for (int rt = 0; rt < 3; rt++) {
#pragma unroll
        for (int rr = 0; rr < 4; rr++) {
            int rw = rt * 16 + quad * 4 + rr;
            long e = e0 + rw;
            if (e < E_TOTAL) {
                float* op = out + e * DOUT + w * 64 + lo;
#pragma unroll
                for (int ct = 0; ct < 4; ct++)
                    op[ct * 16] = oacc[rt][ct][rr] + bv[ct];
            }
        }
    }
}

extern "C" void kernel_launch(void* const* d_in, const int* in_sizes, int n_in,
                              void* d_out, int out_size, void* d_ws, size_t ws_size,
                              hipStream_t stream) {
    const float* x   = (const float*)d_in[0];
    const int*   ei  = (const int*)d_in[1];
    const float* W1  = (const float*)d_in[2];
    const float* b1  = (const float*)d_in[3];
    const float* W2  = (const float*)d_in[4];
    const float* b2  = (const float*)d_in[5];
    float* out = (float*)d_out;

    // workspace layout (bytes):
    //   xb   5,120,000
    //   Wcp/W1p 524,288  @ 5,120,000
    //   W2p     262,144  @ 5,644,288
    //   flag         64  @ 5,906,432
    //   P           ...  @ 5,906,496  (bf16: 20,480,000)
    unsigned short* xb  = (unsigned short*)d_ws;
    unsigned short* Wcp = (unsigned short*)((char*)d_ws + 5120000);
    unsigned short* W2p = (unsigned short*)((char*)d_ws + 5644288);
    int* flag = (int*)((char*)d_ws + 5906432);
    void* P = (void*)((char*)d_ws + 5906496);
    const size_t NEED_BF16 = 5906496ull + 20480000ull;

    hipLaunchKernelGGL(detect_i64, dim3(1), dim3(256), 0, stream, ei, flag);
    hipLaunchKernelGGL(convert_x, dim3(1024), dim3(256), 0, stream, x, xb);
    hipLaunchKernelGGL(pack_w, dim3(64), dim3(256), 0, stream, W2, W2p, DOUT, 16, 16);

    if (ws_size >= NEED_BF16) {
        hipLaunchKernelGGL(pack_wcat, dim3(128), dim3(256), 0, stream, W1, Wcp);
        hipLaunchKernelGGL((node_gemm<false>), dim3(157, 4), dim3(256), 0, stream, xb, Wcp, P);
        hipLaunchKernelGGL((edge_out<false>), dim3(5000), dim3(512), 0, stream,
                           P, ei, b1, W2p, b2, flag, out);
    } else {
        hipLaunchKernelGGL(pack_w, dim3(128), dim3(256), 0, stream, W1, Wcp, HDIM, 32, 16);
        hipLaunchKernelGGL(edge_mlp, dim3(N_MAIN_BLOCKS), dim3(256), 0, stream,
                           xb, ei, b1, Wcp, b2, W2p, flag, out);
    }
}